// Round 8
// baseline (194.414 us; speedup 1.0000x reference)
//
#include <hip/hip_runtime.h>
#include <math.h>

// Problem constants (match reference setup_inputs)
#define SB 196   // spatial s = h*w = 14*14
#define SP 224   // s padded to 7*32 for MFMA K-steps (k3)
#define NB 8     // batch
#define NC 2048  // channels
#define ND 1024  // INTER_DIM
#define NN 80    // NUM_CLASSES
#define NW 300   // WORD_DIM
#define CH 16    // d-chunks = k1 d-tiles (64 d each); k2b sums 16
#define NJ (NB * SB)   // combined (b,s) = 1568
#define NJP 1600       // padded to 25 tiles of 64
#define PITCH 40       // LDS row pitch (bank-conflict-free, proven)

typedef __bf16 v8bf __attribute__((ext_vector_type(8)));
typedef __bf16 v4bf __attribute__((ext_vector_type(4)));
typedef float  f32x4 __attribute__((ext_vector_type(4)));

// ---------------------------------------------------------------------------
// kprep (NEW R8): tiny producer dispatch for everything k0_fwd needs.
// grid 148 blocks: [0,64)  vpart[e-slice][d] = partial Wa.W3 column sums
//                  [64,144) W2t transpose tiles (W2 [1024][300] -> [300][1024])
//                  [144,148) zero Xt pad rows [1568,1600)
// ---------------------------------------------------------------------------
__global__ __launch_bounds__(256) void kprep(const float* __restrict__ W2,
                                             const float* __restrict__ W3,
                                             const float* __restrict__ Wa,
                                             float* __restrict__ vpart,
                                             float* __restrict__ W2t,
                                             __bf16* __restrict__ Xt) {
    const int t = threadIdx.x;
    const int bid = blockIdx.x;
    if (bid < 64) {
        const int e0 = (bid >> 2) * 64;
        const int d  = (bid & 3) * 256 + t;
        float p = 0.f;
        #pragma unroll 8
        for (int e = e0; e < e0 + 64; ++e)
            p += Wa[e] * W3[(size_t)e * ND + d];   // coalesced over d
        vpart[(bid >> 2) * ND + d] = p;
    } else if (bid < 144) {
        __shared__ float tw[64][65];
        int id = bid - 64;                  // 0..79
        int dt = id / 5, wt = id - dt * 5;
        int d0 = dt * 64, w0 = wt * 64;
        {   // read coalesced over w
            int ss = t & 63, cbase = t >> 6;
            #pragma unroll
            for (int r = 0; r < 16; ++r) {
                int cc = cbase + 4 * r;
                tw[cc][ss] = (w0 + ss < NW) ? W2[(size_t)(d0 + cc) * NW + w0 + ss] : 0.f;
            }
        }
        __syncthreads();
        {   // write coalesced over d
            int cc = t & 63, sbase = t >> 6;
            #pragma unroll
            for (int r = 0; r < 16; ++r) {
                int ss = sbase + 4 * r;
                if (w0 + ss < NW)
                    W2t[(size_t)(w0 + ss) * ND + d0 + cc] = tw[cc][ss];
            }
        }
    } else {
        // zero Xt pad rows: 32 rows x 2048 bf16 = 8192 uint4 over 4 blocks
        const int tid = (bid - 144) * 256 + t;   // 0..1023
        uint4 z = make_uint4(0u, 0u, 0u, 0u);
        uint4* p = (uint4*)(Xt + (size_t)NJ * NC);
        #pragma unroll
        for (int r = 0; r < 8; ++r) p[tid + r * 1024] = z;
    }
}

// ---------------------------------------------------------------------------
// kcast_x: X pass (z<8), W1 cast (z==8), and k0_fwd (z>=9, moved here from k1
// because k1's GEMM blocks now CONSUME wpack — same-dispatch production would
// race). k0_fwd reads vpart/W2t from kprep (previous dispatch, ordered).
// grid (32, 4, 12): z in [9,12) gives 384 slots; e<320 do k0_fwd, rest idle.
// ---------------------------------------------------------------------------
__global__ __launch_bounds__(256) void kcast_x(const float* __restrict__ X,
                                               const float* __restrict__ W1,
                                               const float* __restrict__ word,
                                               const float* __restrict__ vpart,
                                               const float* __restrict__ W2t,
                                               __bf16* __restrict__ Xt,
                                               __bf16* __restrict__ Xhi,
                                               __bf16* __restrict__ Xlo,
                                               __bf16* __restrict__ W1b,
                                               float2* __restrict__ wpack) {
    const int t = threadIdx.x;
    if (blockIdx.z >= 9) {
        // fused k0_fwd: wpack[n][d] = { 2*log2(e)*(word[n].W2[d]), -2*v[d] }
        // 320 blocks; e: n = e>>2, d-range (e&3)*256 + t. W2t read coalesced.
        const int e = (blockIdx.z - 9) * 128 + blockIdx.x * 4 + blockIdx.y;
        if (e >= 320) return;
        __shared__ __align__(16) float lword[NW];
        const int n = e >> 2;
        const int d = (e & 3) * 256 + t;
        for (int i = t; i < NW; i += 256) lword[i] = word[(size_t)n * NW + i];
        __syncthreads();
        float acc = 0.f;
        #pragma unroll 10
        for (int w = 0; w < NW; ++w)
            acc = fmaf(lword[w], W2t[(size_t)w * ND + d], acc);   // coalesced
        float vv = 0.f;
        #pragma unroll
        for (int p = 0; p < 16; ++p) vv += vpart[p * ND + d];
        float2 o;
        o.x = 2.8853900817779268f * acc;   // 2*log2(e) * fwd[n][d]
        o.y = -2.f * vv;
        wpack[(size_t)n * ND + d] = o;
        return;
    }
    if (blockIdx.z == 8) {
        // W1 cast: 128 blocks x 256 threads x 16 float4 = 2M elems
        unsigned int slice_tid = (blockIdx.x * 4 + blockIdx.y) * 256 + t;
        #pragma unroll 4
        for (int r = 0; r < 16; ++r) {
            size_t i = ((size_t)slice_tid + (size_t)r * 32768) * 4;
            float4 f = *(const float4*)(W1 + i);
            v4bf o;
            o[0] = (__bf16)f.x; o[1] = (__bf16)f.y;
            o[2] = (__bf16)f.z; o[3] = (__bf16)f.w;
            *(v4bf*)(W1b + i) = o;
        }
        return;
    }
    __shared__ float tile[64][65];   // [c][s], +1 pad
    const int b  = blockIdx.z;
    const int c0 = blockIdx.x * 64;
    const int s0 = blockIdx.y * 64;
    const float* Xb = X + (size_t)b * NC * SB;
    {   // read: coalesced over s
        int ss = t & 63, cbase = t >> 6;
        #pragma unroll
        for (int r = 0; r < 16; ++r) {
            int cc = cbase + 4 * r;
            float val = (s0 + ss < SB) ? Xb[(size_t)(c0 + cc) * SB + s0 + ss] : 0.f;
            tile[cc][ss] = val;
        }
    }
    __syncthreads();
    {   // write 1: Xt transposed, coalesced over c
        int cc = t & 63, sbase = t >> 6;
        #pragma unroll
        for (int r = 0; r < 16; ++r) {
            int ss = sbase + 4 * r;
            if (s0 + ss < SB)
                Xt[((size_t)b * SB + s0 + ss) * NC + c0 + cc] = (__bf16)tile[cc][ss];
        }
    }
    {   // write 2: Xhi/Xlo direct orientation, coalesced over s; zero the pad
        int ss = t & 63, cbase = t >> 6;
        int sg = s0 + ss;
        #pragma unroll
        for (int r = 0; r < 16; ++r) {
            int cc = cbase + 4 * r;
            if (sg < SP) {
                float val = (sg < SB) ? tile[cc][ss] : 0.f;
                __bf16 h = (__bf16)val;
                __bf16 l = (__bf16)(val - (float)h);
                size_t base = ((size_t)b * NC + c0 + cc) * SP + sg;
                Xhi[base] = h;
                Xlo[base] = l;
            }
        }
    }
}

// ---------------------------------------------------------------------------
// K1 (MFMA + fused sigmoid epilogue, R8): per block (d-tile ch, j-tile),
// GEMM F_tile = W1[64d] x Xt[64j] (R0-proven reg-staging loop), round-trip
// the tile through LDS (reusing the staging buffer), then
//   part[ch][b][n][s] = sum_{d in tile} wy/(1 + 2^(F*wx))
// wave w handles n in [20w,20w+20), lane <-> j: the 64-d sum is LANE-LOCAL
// (no cross-lane reduce); wpack rows are wave-uniform s_loads; part write is
// coalesced over s. F buffer ELIMINATED (write + 128 MB L2 re-reads + k2a
// dispatch all gone). grid (16 d-tiles, 25 j-tiles).
// ---------------------------------------------------------------------------
__global__ __launch_bounds__(256) void k1_mfma(const __bf16* __restrict__ Xt,
                                               const __bf16* __restrict__ W1b,
                                               const float2* __restrict__ wpack,
                                               float* __restrict__ part) {
    __shared__ __align__(16) char smem[64 * 65 * 4];   // 16.6 KB union
    __bf16* lA    = (__bf16*)smem;          // 64*PITCH bf16 (5 KB)
    __bf16* lB    = lA + 64 * PITCH;        // 64*PITCH bf16 (5 KB)
    float*  Ftile = (float*)smem;           // 64 x 65 fp32 (epilogue reuse)

    const int t    = threadIdx.x;
    const int d0   = blockIdx.x * 64;
    const int j0   = blockIdx.y * 64;
    const int lane = t & 63;
    const int wave = t >> 6;
    const int doff = (wave & 1) * 32;
    const int joff = (wave >> 1) * 32;
    const int quad = lane >> 4;
    const int l16  = lane & 15;

    f32x4 acc[2][2] = {};

    const int rr = t >> 2;
    const int cc = (t & 3) * 8;
    const __bf16* Ag = W1b + (size_t)(d0 + rr) * NC + cc;
    const __bf16* Bg = Xt + (size_t)(j0 + rr) * NC + cc;   // pad rows are zero
    __bf16* lAw = lA + rr * PITCH + cc;
    __bf16* lBw = lB + rr * PITCH + cc;

    const __bf16* rA0 = lA + (doff + l16) * PITCH + quad * 8;
    const __bf16* rA1 = rA0 + 16 * PITCH;
    const __bf16* rB0 = lB + (joff + l16) * PITCH + quad * 8;
    const __bf16* rB1 = rB0 + 16 * PITCH;

    for (int k0 = 0; k0 < NC; k0 += 32) {
        uint4 a  = *(const uint4*)(Ag + k0);
        uint4 bv = *(const uint4*)(Bg + k0);
        __syncthreads();
        *(uint4*)lAw = a;
        *(uint4*)lBw = bv;
        __syncthreads();
        v8bf a0 = *(const v8bf*)rA0;
        v8bf a1 = *(const v8bf*)rA1;
        v8bf b0 = *(const v8bf*)rB0;
        v8bf b1 = *(const v8bf*)rB1;
        acc[0][0] = __builtin_amdgcn_mfma_f32_16x16x32_bf16(a0, b0, acc[0][0], 0, 0, 0);
        acc[0][1] = __builtin_amdgcn_mfma_f32_16x16x32_bf16(a0, b1, acc[0][1], 0, 0, 0);
        acc[1][0] = __builtin_amdgcn_mfma_f32_16x16x32_bf16(a1, b0, acc[1][0], 0, 0, 0);
        acc[1][1] = __builtin_amdgcn_mfma_f32_16x16x32_bf16(a1, b1, acc[1][1], 0, 0, 0);
    }

    // ---- epilogue: acc -> LDS F-tile (overwrites staging buffer) ----
    __syncthreads();   // all waves done with lA/lB reads
    #pragma unroll
    for (int i = 0; i < 2; ++i) {
        #pragma unroll
        for (int jj = 0; jj < 2; ++jj) {
            #pragma unroll
            for (int r = 0; r < 4; ++r) {
                Ftile[(doff + i * 16 + quad * 4 + r) * 65 + (joff + jj * 16 + l16)]
                    = acc[i][jj][r];
            }
        }
    }
    __syncthreads();

    // ---- sigmoid-sum: wave w -> n in [20w,20w+20), lane <-> j ----
    const int wid   = __builtin_amdgcn_readfirstlane(wave);
    const int jglob = j0 + lane;
    const bool valid = jglob < NJ;
    const int bi = jglob / SB;
    const int s  = jglob - bi * SB;
    const int ch = blockIdx.x;
    for (int nn = 0; nn < 20; ++nn) {
        const int n = wid * 20 + nn;
        const float2* wrow = wpack + (size_t)n * ND + d0;   // wave-uniform
        float p = 0.f;
        #pragma unroll 8
        for (int dd = 0; dd < 64; ++dd) {
            float2 w  = wrow[dd];                 // s_load (scalar) pair
            float  Fv = Ftile[dd * 65 + lane];    // ds_read, conflict-free
            p = fmaf(w.y, __builtin_amdgcn_rcpf(1.f + __builtin_amdgcn_exp2f(Fv * w.x)), p);
        }
        if (valid)
            part[(((size_t)ch * NB + bi) * NN + n) * 256 + s] = p;
    }
}

// ---------------------------------------------------------------------------
// K2b: sum 16 chunks, softmax over s, write split bf16 coef (SP-padded).
// grid (80 n, 8 b), block 256. UNCHANGED (R6-proven, CH=16).
// ---------------------------------------------------------------------------
__global__ __launch_bounds__(256) void k2b(const float* __restrict__ part,
                                           __bf16* __restrict__ coefh,
                                           __bf16* __restrict__ coefl) {
    __shared__ float red[256];
    const int n = blockIdx.x;
    const int b = blockIdx.y;
    const int t = threadIdx.x;
    float acc = 0.f;
    #pragma unroll
    for (int ch = 0; ch < CH; ++ch)
        acc += part[(((size_t)ch * NB + b) * NN + n) * 256 + t];

    red[t] = (t < SB) ? acc : -1e30f;
    __syncthreads();
    #pragma unroll
    for (int off = 128; off > 0; off >>= 1) {
        if (t < off) red[t] = fmaxf(red[t], red[t + off]);
        __syncthreads();
    }
    float m = red[0];
    __syncthreads();
    float p = (t < SB) ? __expf(acc - m) : 0.f;
    red[t] = p;
    __syncthreads();
    #pragma unroll
    for (int off = 128; off > 0; off >>= 1) {
        if (t < off) red[t] += red[t + off];
        __syncthreads();
    }
    float inv = 1.f / red[0];
    if (t < SP) {
        float val = (t < SB) ? p * inv : 0.f;
        __bf16 h = (__bf16)val;
        __bf16 l = (__bf16)(val - (float)h);
        size_t base = ((size_t)b * NN + n) * SP + t;
        coefh[base] = h;
        coefl[base] = l;
    }
}

// ---------------------------------------------------------------------------
// K3 (MFMA, split precision): out[b][n][c] = sum_s coef[b][n][s] * X[b][c][s]
// out ~= Ah*Bh + Al*Bh + Ah*Bl. grid (32 c-tiles, 8 b). UNCHANGED (proven).
// ---------------------------------------------------------------------------
__global__ __launch_bounds__(256) void k3_mfma(const __bf16* __restrict__ Xhi,
                                               const __bf16* __restrict__ Xlo,
                                               const __bf16* __restrict__ coefh,
                                               const __bf16* __restrict__ coefl,
                                               float* __restrict__ out) {
    const int t     = threadIdx.x;
    const int wave  = t >> 6;
    const int lane  = t & 63;
    const int quad  = lane >> 4;
    const int l16   = lane & 15;
    const int b     = blockIdx.y;
    const int cbase = blockIdx.x * 64 + wave * 16;

    const __bf16* Bh = Xhi + ((size_t)b * NC + cbase + l16) * SP + quad * 8;
    const __bf16* Bl = Xlo + ((size_t)b * NC + cbase + l16) * SP + quad * 8;
    const __bf16* Ah = coefh + ((size_t)b * NN + l16) * SP + quad * 8;
    const __bf16* Al = coefl + ((size_t)b * NN + l16) * SP + quad * 8;

    f32x4 acc[5] = {};

    #pragma unroll
    for (int k0 = 0; k0 < SP; k0 += 32) {
        v8bf bh = *(const v8bf*)(Bh + k0);
        v8bf bl = *(const v8bf*)(Bl + k0);
        #pragma unroll
        for (int mt = 0; mt < 5; ++mt) {
            v8bf ah = *(const v8bf*)(Ah + (size_t)mt * 16 * SP + k0);
            v8bf al = *(const v8bf*)(Al + (size_t)mt * 16 * SP + k0);
            acc[mt] = __builtin_amdgcn_mfma_f32_16x16x32_bf16(ah, bh, acc[mt], 0, 0, 0);
            acc[mt] = __builtin_amdgcn_mfma_f32_16x16x32_bf16(al, bh, acc[mt], 0, 0, 0);
            acc[mt] = __builtin_amdgcn_mfma_f32_16x16x32_bf16(ah, bl, acc[mt], 0, 0, 0);
        }
    }
    #pragma unroll
    for (int mt = 0; mt < 5; ++mt) {
        #pragma unroll
        for (int r = 0; r < 4; ++r) {
            int n = mt * 16 + quad * 4 + r;
            out[((size_t)b * NN + n) * NC + cbase + l16] = acc[mt][r];
        }
    }
}

// ---------------------------------------------------------------------------
// Workspace layout — NO aliasing; F buffer ELIMINATED (peak use ~36 MB):
//   vpart(64K) | W2t(1.2M) | wpack(640K) | part(8.39M) | coefh(280K) |
//   coefl(280K) | W1b(4M) | Xt(6.55M) | Xhi(7.34M) | Xlo(7.34M)
// Pipeline: kprep -> kcast_x(+k0_fwd) -> k1(GEMM+sigmoid) -> k2b -> k3
// ---------------------------------------------------------------------------
extern "C" void kernel_launch(void* const* d_in, const int* in_sizes, int n_in,
                              void* d_out, int out_size, void* d_ws, size_t ws_size,
                              hipStream_t stream) {
    const float* X    = (const float*)d_in[0];  // [8][2048][196]
    const float* word = (const float*)d_in[1];  // [80][300]
    const float* W1   = (const float*)d_in[2];  // [1024][2048]
    const float* W2   = (const float*)d_in[3];  // [1024][300]
    const float* W3   = (const float*)d_in[4];  // [1024][1024]
    // d_in[5] = b3, d_in[7] = ba: cancel in softmax (uniform over s) -> unused
    const float* Wa   = (const float*)d_in[6];  // [1][1024]
    float* out = (float*)d_out;

    char* ws = (char*)d_ws;
    float*  vpart = (float*)ws;                             // 16*1024 f
    float*  W2t   = vpart + 16 * ND;                        // 300*1024 f
    float2* wpack = (float2*)(W2t + (size_t)NW * ND);       // 80*1024 float2
    float*  part  = (float*)(wpack + (size_t)NN * ND);      // 16*8*80*256 f
    __bf16* coefh = (__bf16*)(part + (size_t)CH * NB * NN * 256);
    __bf16* coefl = coefh + (size_t)NB * NN * SP;
    __bf16* W1b   = coefl + (size_t)NB * NN * SP;           // 4.00 MB
    __bf16* Xt    = W1b + (size_t)ND * NC;                  // 6.55 MB (1600 rows)
    __bf16* Xhi   = Xt + (size_t)NJP * NC;                  // 7.34 MB
    __bf16* Xlo   = Xhi + (size_t)NB * NC * SP;             // 7.34 MB

    kprep  <<<148,               256, 0, stream>>>(W2, W3, Wa, vpart, W2t, Xt);
    kcast_x<<<dim3(32, 4, 12),   256, 0, stream>>>(X, W1, word, vpart, W2t, Xt, Xhi, Xlo, W1b, wpack);
    k1_mfma<<<dim3(16, 25),      256, 0, stream>>>(Xt, W1b, wpack, part);
    k2b    <<<dim3(NN, NB),      256, 0, stream>>>(part, coefh, coefl);
    k3_mfma<<<dim3(NC / 64, NB), 256, 0, stream>>>(Xhi, Xlo, coefh, coefl, out);
}

// Round 9
// 164.832 us; speedup vs baseline: 1.1795x; 1.1795x over previous
//
#include <hip/hip_runtime.h>
#include <math.h>

// Problem constants (match reference setup_inputs)
#define SB 196   // spatial s = h*w = 14*14
#define SP 224   // s padded to 7*32 for MFMA K-steps (k3)
#define NB 8     // batch
#define NC 2048  // channels
#define ND 1024  // INTER_DIM
#define NN 80    // NUM_CLASSES
#define NW 300   // WORD_DIM
#define CH 16    // d-chunks in k2a (R6-proven)
#define DCH (ND / CH)
#define NT 4     // n-tiling in k2a (proven)
#define NJ (NB * SB)   // combined (b,s) = 1568
#define NJP 1600       // padded to 25 tiles of 64
#define PITCH 40       // LDS row pitch (bank-conflict-free, proven)

typedef __bf16 v8bf __attribute__((ext_vector_type(8)));
typedef __bf16 v4bf __attribute__((ext_vector_type(4)));
typedef float  f32x4 __attribute__((ext_vector_type(4)));

// ---------------------------------------------------------------------------
// kcast_x: ONE pass over X [b][c][s] fp32 producing
//   Xt  [j=b*196+s][c] bf16 (transposed; rows 1568..1599 zeroed)
//   Xhi/Xlo [b][c][224] bf16 split (for k3), zero s-pad
// grid (32, 4, 10): z<8 batch slice; z==8 W1 cast; z==9 vpart + Xt pad zero.
// UNCHANGED (R6-proven).
// ---------------------------------------------------------------------------
__global__ __launch_bounds__(256) void kcast_x(const float* __restrict__ X,
                                               const float* __restrict__ W1,
                                               const float* __restrict__ W3,
                                               const float* __restrict__ Wa,
                                               __bf16* __restrict__ Xt,
                                               __bf16* __restrict__ Xhi,
                                               __bf16* __restrict__ Xlo,
                                               __bf16* __restrict__ W1b,
                                               float* __restrict__ vpart) {
    const int t = threadIdx.x;
    if (blockIdx.z == 9) {
        if (blockIdx.x < 16) {
            const int e0 = blockIdx.x * 64;
            const int d  = blockIdx.y * 256 + t;
            float p = 0.f;
            #pragma unroll 8
            for (int e = e0; e < e0 + 64; ++e)
                p += Wa[e] * W3[(size_t)e * ND + d];   // coalesced over d
            vpart[blockIdx.x * ND + d] = p;
        } else if (blockIdx.x == 16) {
            const int tid = blockIdx.y * 256 + t;      // 0..1023
            uint4 z = make_uint4(0u, 0u, 0u, 0u);
            uint4* p = (uint4*)(Xt + (size_t)NJ * NC);
            #pragma unroll
            for (int r = 0; r < 8; ++r) p[tid + r * 1024] = z;
        }
        return;
    }
    if (blockIdx.z == 8) {
        unsigned int slice_tid = (blockIdx.x * 4 + blockIdx.y) * 256 + t;
        #pragma unroll 4
        for (int r = 0; r < 16; ++r) {
            size_t i = ((size_t)slice_tid + (size_t)r * 32768) * 4;
            float4 f = *(const float4*)(W1 + i);
            v4bf o;
            o[0] = (__bf16)f.x; o[1] = (__bf16)f.y;
            o[2] = (__bf16)f.z; o[3] = (__bf16)f.w;
            *(v4bf*)(W1b + i) = o;
        }
        return;
    }
    __shared__ float tile[64][65];   // [c][s], +1 pad
    const int b  = blockIdx.z;
    const int c0 = blockIdx.x * 64;
    const int s0 = blockIdx.y * 64;
    const float* Xb = X + (size_t)b * NC * SB;
    {   // read: coalesced over s
        int ss = t & 63, cbase = t >> 6;
        #pragma unroll
        for (int r = 0; r < 16; ++r) {
            int cc = cbase + 4 * r;
            float val = (s0 + ss < SB) ? Xb[(size_t)(c0 + cc) * SB + s0 + ss] : 0.f;
            tile[cc][ss] = val;
        }
    }
    __syncthreads();
    {   // write 1: Xt transposed, coalesced over c
        int cc = t & 63, sbase = t >> 6;
        #pragma unroll
        for (int r = 0; r < 16; ++r) {
            int ss = sbase + 4 * r;
            if (s0 + ss < SB)
                Xt[((size_t)b * SB + s0 + ss) * NC + c0 + cc] = (__bf16)tile[cc][ss];
        }
    }
    {   // write 2: Xhi/Xlo, coalesced over s; zero the pad
        int ss = t & 63, cbase = t >> 6;
        int sg = s0 + ss;
        #pragma unroll
        for (int r = 0; r < 16; ++r) {
            int cc = cbase + 4 * r;
            if (sg < SP) {
                float val = (sg < SB) ? tile[cc][ss] : 0.f;
                __bf16 h = (__bf16)val;
                __bf16 l = (__bf16)(val - (float)h);
                size_t base = ((size_t)b * NC + c0 + cc) * SP + sg;
                Xhi[base] = h;
                Xlo[base] = l;
            }
        }
    }
}

// ---------------------------------------------------------------------------
// K1 (MFMA, R9 split-K): F[b][d][s] = sum_c W1[d][c] * X[j=(b,s)][c].
// Block = 512 threads (8 waves). Waves 0-3 accumulate K in [0,1024),
// waves 4-7 K in [1024,2048) — each half runs the R0-proven PITCH-40
// reg-staging loop on its OWN LDS buffers (32 K-steps vs 64: half the
// serial chain, 2x the waves/SIMD vs R6; R8 showed k1 is latency-bound
// at 1.56 waves/SIMD). 2-barrier LDS reduce merges the halves.
// grid (16, 45): y<25 GEMM; y in [25,45) = fused k0_fwd (R3-proven shape,
// guarded to t<256 with barrier-safe structure for the 512-thread block).
// ---------------------------------------------------------------------------
__global__ __launch_bounds__(512) void k1_mfma(const __bf16* __restrict__ Xt,
                                               const __bf16* __restrict__ W1b,
                                               float* __restrict__ F,
                                               const float* __restrict__ word,
                                               const float* __restrict__ W2,
                                               const float* __restrict__ vpart,
                                               float2* __restrict__ wpack) {
    const int t = threadIdx.x;
    if (blockIdx.y >= 25) {
        // fused k0_fwd: wpack[n][d] = { 2*log2(e)*(word[n].W2[d]), -2*v[d] }
        __shared__ __align__(16) float lword[NW];
        const int e = (blockIdx.y - 25) * 16 + blockIdx.x;   // 0..319
        const int n = e >> 2;
        if (t < 256) {
            for (int i = t; i < NW; i += 256) lword[i] = word[(size_t)n * NW + i];
        }
        __syncthreads();   // all 8 waves arrive (barrier-safe)
        if (t < 256) {
            const int d = (e & 3) * 256 + t;
            const float4* wr = (const float4*)(W2 + (size_t)d * NW);
            const float4* l4 = (const float4*)lword;
            float acc = 0.f;
            #pragma unroll 5
            for (int i = 0; i < NW / 4; ++i) {
                float4 a = wr[i], b = l4[i];
                acc += a.x * b.x + a.y * b.y + a.z * b.z + a.w * b.w;
            }
            float vv = 0.f;
            #pragma unroll
            for (int p = 0; p < 16; ++p) vv += vpart[p * ND + d];
            float2 o;
            o.x = 2.8853900817779268f * acc;   // 2*log2(e) * fwd[n][d]
            o.y = -2.f * vv;
            wpack[(size_t)n * ND + d] = o;
        }
        return;
    }
    // ---- GEMM, split-K across the two 4-wave halves ----
    __shared__ __align__(16) char smem[4 * 64 * PITCH * 2];   // 20.5 KB
    const int half = t >> 8;         // 0: K [0,1024), 1: K [1024,2048)
    const int tt   = t & 255;        // thread id within half
    __bf16* lA = (__bf16*)smem + half * 64 * PITCH;
    __bf16* lB = (__bf16*)smem + 2 * 64 * PITCH + half * 64 * PITCH;
    float*  red = (float*)smem;      // 64x64 f32 reduce buffer (16 KB, reused)

    const int d0   = blockIdx.x * 64;
    const int j0   = blockIdx.y * 64;
    const int lane = tt & 63;
    const int w4   = tt >> 6;        // wave index within half, 0..3
    const int doff = (w4 & 1) * 32;
    const int joff = (w4 >> 1) * 32;
    const int quad = lane >> 4;
    const int l16  = lane & 15;

    f32x4 acc[2][2] = {};

    const int rr = tt >> 2;
    const int cc = (tt & 3) * 8;
    const int kbase = half * (NC / 2);
    const __bf16* Ag = W1b + (size_t)(d0 + rr) * NC + kbase + cc;
    const __bf16* Bg = Xt + (size_t)(j0 + rr) * NC + kbase + cc;  // pad rows zero
    __bf16* lAw = lA + rr * PITCH + cc;
    __bf16* lBw = lB + rr * PITCH + cc;

    const __bf16* rA0 = lA + (doff + l16) * PITCH + quad * 8;
    const __bf16* rA1 = rA0 + 16 * PITCH;
    const __bf16* rB0 = lB + (joff + l16) * PITCH + quad * 8;
    const __bf16* rB1 = rB0 + 16 * PITCH;

    for (int k0 = 0; k0 < NC / 2; k0 += 32) {
        uint4 a  = *(const uint4*)(Ag + k0);
        uint4 bv = *(const uint4*)(Bg + k0);
        __syncthreads();
        *(uint4*)lAw = a;
        *(uint4*)lBw = bv;
        __syncthreads();
        v8bf a0 = *(const v8bf*)rA0;
        v8bf a1 = *(const v8bf*)rA1;
        v8bf b0 = *(const v8bf*)rB0;
        v8bf b1 = *(const v8bf*)rB1;
        acc[0][0] = __builtin_amdgcn_mfma_f32_16x16x32_bf16(a0, b0, acc[0][0], 0, 0, 0);
        acc[0][1] = __builtin_amdgcn_mfma_f32_16x16x32_bf16(a0, b1, acc[0][1], 0, 0, 0);
        acc[1][0] = __builtin_amdgcn_mfma_f32_16x16x32_bf16(a1, b0, acc[1][0], 0, 0, 0);
        acc[1][1] = __builtin_amdgcn_mfma_f32_16x16x32_bf16(a1, b1, acc[1][1], 0, 0, 0);
    }

    __syncthreads();   // staging reads done everywhere; safe to reuse smem
    if (half == 1) {   // upper half deposits its partial sums
        #pragma unroll
        for (int i = 0; i < 2; ++i)
            #pragma unroll
            for (int jj = 0; jj < 2; ++jj)
                #pragma unroll
                for (int r = 0; r < 4; ++r)
                    red[(doff + i * 16 + quad * 4 + r) * 64 + (joff + jj * 16 + l16)]
                        = acc[i][jj][r];
    }
    __syncthreads();
    if (half == 0) {   // lower half merges and stores F
        #pragma unroll
        for (int i = 0; i < 2; ++i) {
            #pragma unroll
            for (int jj = 0; jj < 2; ++jj) {
                int j = j0 + joff + jj * 16 + l16;
                if (j < NJ) {
                    int b = j / SB;
                    int s = j - b * SB;
                    float* Fp = F + ((size_t)b * ND + d0 + doff + i * 16 + quad * 4) * SB + s;
                    #pragma unroll
                    for (int r = 0; r < 4; ++r) {
                        float v = acc[i][jj][r]
                                + red[(doff + i * 16 + quad * 4 + r) * 64 + (joff + jj * 16 + l16)];
                        Fp[(size_t)r * SB] = v;
                    }
                }
            }
        }
    }
}

// ---------------------------------------------------------------------------
// K2a: partial logits, NT=4 n-tiling, CH=16 d-chunks.
// grid (20, 7, 16) = 2240 blocks (R6-proven: 35 waves/CU). UNCHANGED.
// ---------------------------------------------------------------------------
__global__ __launch_bounds__(256) void k2a(const float* __restrict__ F,
                                           const float2* __restrict__ wpack,
                                           float* __restrict__ part) {
    const int n0  = blockIdx.x * NT;
    const int ch  = blockIdx.z;
    const int idx = blockIdx.y * 256 + threadIdx.x;   // (b,s) flat, valid <1568
    const bool valid = idx < (NB * SB);
    const int iv = valid ? idx : 0;
    const int b  = iv / SB;
    const int s  = iv - b * SB;
    const float*  Fp  = F + ((size_t)b * ND + ch * DCH) * SB + s;
    const float4* wp0 = (const float4*)(wpack + (size_t)(n0 + 0) * ND + ch * DCH);
    const float4* wp1 = (const float4*)(wpack + (size_t)(n0 + 1) * ND + ch * DCH);
    const float4* wp2 = (const float4*)(wpack + (size_t)(n0 + 2) * ND + ch * DCH);
    const float4* wp3 = (const float4*)(wpack + (size_t)(n0 + 3) * ND + ch * DCH);
    float a0 = 0.f, a1 = 0.f, a2 = 0.f, a3 = 0.f;
    #pragma unroll 4
    for (int d2 = 0; d2 < DCH / 2; ++d2) {
        float f0 = Fp[(size_t)(2 * d2)     * SB];
        float f1 = Fp[(size_t)(2 * d2 + 1) * SB];
        float4 w0 = wp0[d2];   // {wx0, wy0, wx1, wy1} wave-uniform s_load
        float4 w1 = wp1[d2];
        float4 w2 = wp2[d2];
        float4 w3 = wp3[d2];
        float e00 = __builtin_amdgcn_exp2f(f0 * w0.x);
        float e01 = __builtin_amdgcn_exp2f(f1 * w0.z);
        float e10 = __builtin_amdgcn_exp2f(f0 * w1.x);
        float e11 = __builtin_amdgcn_exp2f(f1 * w1.z);
        float e20 = __builtin_amdgcn_exp2f(f0 * w2.x);
        float e21 = __builtin_amdgcn_exp2f(f1 * w2.z);
        float e30 = __builtin_amdgcn_exp2f(f0 * w3.x);
        float e31 = __builtin_amdgcn_exp2f(f1 * w3.z);
        a0 = fmaf(w0.y, __builtin_amdgcn_rcpf(1.f + e00), a0);
        a0 = fmaf(w0.w, __builtin_amdgcn_rcpf(1.f + e01), a0);
        a1 = fmaf(w1.y, __builtin_amdgcn_rcpf(1.f + e10), a1);
        a1 = fmaf(w1.w, __builtin_amdgcn_rcpf(1.f + e11), a1);
        a2 = fmaf(w2.y, __builtin_amdgcn_rcpf(1.f + e20), a2);
        a2 = fmaf(w2.w, __builtin_amdgcn_rcpf(1.f + e21), a2);
        a3 = fmaf(w3.y, __builtin_amdgcn_rcpf(1.f + e30), a3);
        a3 = fmaf(w3.w, __builtin_amdgcn_rcpf(1.f + e31), a3);
    }
    if (valid) {
        size_t base = ((size_t)ch * NB + b) * NN;
        part[(base + n0 + 0) * 256 + s] = a0;
        part[(base + n0 + 1) * 256 + s] = a1;
        part[(base + n0 + 2) * 256 + s] = a2;
        part[(base + n0 + 3) * 256 + s] = a3;
    }
}

// ---------------------------------------------------------------------------
// K2b: sum 16 chunks, softmax over s, write split bf16 coef (SP-padded).
// grid (80 n, 8 b), block 256. UNCHANGED (R6-proven).
// ---------------------------------------------------------------------------
__global__ __launch_bounds__(256) void k2b(const float* __restrict__ part,
                                           __bf16* __restrict__ coefh,
                                           __bf16* __restrict__ coefl) {
    __shared__ float red[256];
    const int n = blockIdx.x;
    const int b = blockIdx.y;
    const int t = threadIdx.x;
    float acc = 0.f;
    #pragma unroll
    for (int ch = 0; ch < CH; ++ch)
        acc += part[(((size_t)ch * NB + b) * NN + n) * 256 + t];

    red[t] = (t < SB) ? acc : -1e30f;
    __syncthreads();
    #pragma unroll
    for (int off = 128; off > 0; off >>= 1) {
        if (t < off) red[t] = fmaxf(red[t], red[t + off]);
        __syncthreads();
    }
    float m = red[0];
    __syncthreads();
    float p = (t < SB) ? __expf(acc - m) : 0.f;
    red[t] = p;
    __syncthreads();
    #pragma unroll
    for (int off = 128; off > 0; off >>= 1) {
        if (t < off) red[t] += red[t + off];
        __syncthreads();
    }
    float inv = 1.f / red[0];
    if (t < SP) {
        float val = (t < SB) ? p * inv : 0.f;
        __bf16 h = (__bf16)val;
        __bf16 l = (__bf16)(val - (float)h);
        size_t base = ((size_t)b * NN + n) * SP + t;
        coefh[base] = h;
        coefl[base] = l;
    }
}

// ---------------------------------------------------------------------------
// K3 (MFMA, split precision): out[b][n][c] = sum_s coef[b][n][s] * X[b][c][s]
// out ~= Ah*Bh + Al*Bh + Ah*Bl. grid (32 c-tiles, 8 b). UNCHANGED (proven).
// ---------------------------------------------------------------------------
__global__ __launch_bounds__(256) void k3_mfma(const __bf16* __restrict__ Xhi,
                                               const __bf16* __restrict__ Xlo,
                                               const __bf16* __restrict__ coefh,
                                               const __bf16* __restrict__ coefl,
                                               float* __restrict__ out) {
    const int t     = threadIdx.x;
    const int wave  = t >> 6;
    const int lane  = t & 63;
    const int quad  = lane >> 4;
    const int l16   = lane & 15;
    const int b     = blockIdx.y;
    const int cbase = blockIdx.x * 64 + wave * 16;

    const __bf16* Bh = Xhi + ((size_t)b * NC + cbase + l16) * SP + quad * 8;
    const __bf16* Bl = Xlo + ((size_t)b * NC + cbase + l16) * SP + quad * 8;
    const __bf16* Ah = coefh + ((size_t)b * NN + l16) * SP + quad * 8;
    const __bf16* Al = coefl + ((size_t)b * NN + l16) * SP + quad * 8;

    f32x4 acc[5] = {};

    #pragma unroll
    for (int k0 = 0; k0 < SP; k0 += 32) {
        v8bf bh = *(const v8bf*)(Bh + k0);
        v8bf bl = *(const v8bf*)(Bl + k0);
        #pragma unroll
        for (int mt = 0; mt < 5; ++mt) {
            v8bf ah = *(const v8bf*)(Ah + (size_t)mt * 16 * SP + k0);
            v8bf al = *(const v8bf*)(Al + (size_t)mt * 16 * SP + k0);
            acc[mt] = __builtin_amdgcn_mfma_f32_16x16x32_bf16(ah, bh, acc[mt], 0, 0, 0);
            acc[mt] = __builtin_amdgcn_mfma_f32_16x16x32_bf16(al, bh, acc[mt], 0, 0, 0);
            acc[mt] = __builtin_amdgcn_mfma_f32_16x16x32_bf16(ah, bl, acc[mt], 0, 0, 0);
        }
    }
    #pragma unroll
    for (int mt = 0; mt < 5; ++mt) {
        #pragma unroll
        for (int r = 0; r < 4; ++r) {
            int n = mt * 16 + quad * 4 + r;
            out[((size_t)b * NN + n) * NC + cbase + l16] = acc[mt][r];
        }
    }
}

// ---------------------------------------------------------------------------
// Workspace layout — NO aliasing (ws ~256 MB; peak use ~44 MB):
//   vpart(64K) | wpack(640K) | part(10.49M) | coefh(280K) | coefl(280K) |
//   W1b(4M) | Xt(6.55M, 1600 rows incl. zero pad) | F(6.42M) |
//   Xhi(7.34M) | Xlo(7.34M)
// Pipeline: kcast_x -> k1(+k0_fwd) -> k2a -> k2b -> k3  (5 dispatches)
// ---------------------------------------------------------------------------
extern "C" void kernel_launch(void* const* d_in, const int* in_sizes, int n_in,
                              void* d_out, int out_size, void* d_ws, size_t ws_size,
                              hipStream_t stream) {
    const float* X    = (const float*)d_in[0];  // [8][2048][196]
    const float* word = (const float*)d_in[1];  // [80][300]
    const float* W1   = (const float*)d_in[2];  // [1024][2048]
    const float* W2   = (const float*)d_in[3];  // [1024][300]
    const float* W3   = (const float*)d_in[4];  // [1024][1024]
    // d_in[5] = b3, d_in[7] = ba: cancel in softmax (uniform over s) -> unused
    const float* Wa   = (const float*)d_in[6];  // [1][1024]
    float* out = (float*)d_out;

    char* ws = (char*)d_ws;
    float*  vpart = (float*)ws;                             // 16*1024 f
    float2* wpack = (float2*)(vpart + 16 * ND);             // 80*1024 float2
    float*  part  = (float*)(wpack + (size_t)NN * ND);      // 16*8*80*256 f
    __bf16* coefh = (__bf16*)(part + (size_t)CH * NB * NN * 256);
    __bf16* coefl = coefh + (size_t)NB * NN * SP;
    __bf16* W1b   = coefl + (size_t)NB * NN * SP;           // 4.00 MB
    __bf16* Xt    = W1b + (size_t)ND * NC;                  // 6.55 MB (1600 rows)
    float*  F     = (float*)(Xt + (size_t)NJP * NC);        // 6.42 MB
    __bf16* Xhi   = (__bf16*)(F + (size_t)NB * ND * SB);    // 7.34 MB
    __bf16* Xlo   = Xhi + (size_t)NB * NC * SP;             // 7.34 MB

    kcast_x<<<dim3(32, 4, 10),    256, 0, stream>>>(X, W1, W3, Wa, Xt, Xhi, Xlo, W1b, vpart);
    k1_mfma<<<dim3(16, 45),       512, 0, stream>>>(Xt, W1b, F, word, W2, vpart, wpack);
    k2a    <<<dim3(NN / NT, 7, CH), 256, 0, stream>>>(F, wpack, part);
    k2b    <<<dim3(NN, NB),       256, 0, stream>>>(part, coefh, coefl);
    k3_mfma<<<dim3(NC / 64, NB),  256, 0, stream>>>(Xhi, Xlo, coefh, coefl, out);
}